// Round 1
// baseline (588.804 us; speedup 1.0000x reference)
//
#include <hip/hip_runtime.h>
#include <hip/hip_bf16.h>

#define B_ROWS 1024
#define D_DIM 256
#define Q_N 65536
#define K_TOP 200
#define N_CLASSES 10
#define INV_T 14.2857142857142857f /* 1/0.07 */

typedef unsigned int u32;
typedef unsigned short u16;
typedef unsigned long long u64;

using bf16x8 = __attribute__((ext_vector_type(8))) __bf16;
using f32x4  = __attribute__((ext_vector_type(4))) float;

// ---- helpers ----------------------------------------------------------------

// order-preserving float->uint key (descending float == descending key)
__device__ __forceinline__ u32 fkey(float f) {
  u32 u = __float_as_uint(f);
  return (u >> 31) ? ~u : (u | 0x80000000u);
}
__device__ __forceinline__ float funkey(u32 u) {
  return __uint_as_float((u >> 31) ? (u & 0x7fffffffu) : ~u);
}
__device__ __forceinline__ u16 bf16_rn(float f) {
  u32 u = __float_as_uint(f);
  u32 r = (u + 0x7fffu + ((u >> 16) & 1u)) >> 16;
  return (u16)r;
}
// f ~= hi + lo with hi,lo bf16 (error ~2^-16 relative)
__device__ __forceinline__ void split2(float f, u16& h, u16& l) {
  u16 hh = bf16_rn(f);
  float hf = __uint_as_float(((u32)hh) << 16);
  h = hh;
  l = bf16_rn(f - hf);
}

__device__ __forceinline__ void gl16(const void* g, void* l) {
  __builtin_amdgcn_global_load_lds((const __attribute__((address_space(1))) u32*)g,
                                   (__attribute__((address_space(3))) u32*)l, 16, 0, 0);
}

// ---- kernel 1: x row-normalize + bf16 hi/lo split ---------------------------
__global__ __launch_bounds__(256) void xnorm_k(const float* __restrict__ x,
                                               u16* __restrict__ xh, u16* __restrict__ xl) {
  int row = blockIdx.x, t = threadIdx.x;
  int lane = t & 63, w = t >> 6;
  float v = x[row * D_DIM + t];
  float s = v * v;
  for (int o = 32; o > 0; o >>= 1) s += __shfl_down(s, o);
  __shared__ float ws[4];
  if (lane == 0) ws[w] = s;
  __syncthreads();
  if (t == 0) ws[0] = ws[0] + ws[1] + ws[2] + ws[3];
  __syncthreads();
  float inv = 1.0f / fmaxf(sqrtf(ws[0]), 1e-12f);
  u16 h, l;
  split2(v * inv, h, l);
  xh[row * D_DIM + t] = h;
  xl[row * D_DIM + t] = l;
}

// ---- kernel 2: memory bf16 hi/lo split --------------------------------------
__global__ __launch_bounds__(256) void mdecomp_k(const float4* __restrict__ m,
                                                 ushort4* __restrict__ mh,
                                                 ushort4* __restrict__ ml, int n4) {
  int i = blockIdx.x * blockDim.x + threadIdx.x;
  int stride = gridDim.x * blockDim.x;
  for (; i < n4; i += stride) {
    float4 v = m[i];
    ushort4 h, l;
    split2(v.x, h.x, l.x);
    split2(v.y, h.y, l.y);
    split2(v.z, h.z, l.z);
    split2(v.w, h.w, l.w);
    mh[i] = h;
    ml[i] = l;
  }
}

// ---- kernel 3: dist = A*B^T via bf16x3 MFMA (128x128 tile, BK=32) -----------
// A: [1024][256] (x hi/lo), B: [65536][256] (memory hi/lo), both K-contiguous.
__global__ __launch_bounds__(256) void gemm3_k(const u16* __restrict__ Ah, const u16* __restrict__ Al,
                                               const u16* __restrict__ Bh, const u16* __restrict__ Bl,
                                               float* __restrict__ dist, int row0, int rows) {
  __shared__ u16 sAh[4096], sAl[4096], sBh[4096], sBl[4096];  // 4 x 8KB
  int tid = threadIdx.x;
  int lane = tid & 63, wid = tid >> 6;
  int wr = wid >> 1, wc = wid & 1;
  int col0 = blockIdx.x << 7;
  int trow0 = blockIdx.y << 7;

  // staging: linear LDS, wave-uniform base + lane*16B (global_load_lds contract)
  int e0 = wid * 1024 + lane * 8;  // element offset of j=0 16B block
  int r_s = e0 >> 5, c_s = e0 & 31;
  int ar0 = row0 + trow0 + r_s;
  int ar1 = ar0 + 16;
  ar0 = min(ar0, B_ROWS - 1);  // tail tiles: clamp (store-guarded anyway)
  ar1 = min(ar1, B_ROWS - 1);
  int br0 = col0 + r_s, br1 = br0 + 16;

  // fragment addressing: A lane: row=lane&15, k=(lane>>4)*8+j  (K-contiguous LDS)
  int fr = lane & 15, fq = lane >> 4;
  int a_off0 = (wr * 64 + fr) * 32 + fq * 8;
  int b_off0 = (wc * 64 + fr) * 32 + fq * 8;

  f32x4 acc[4][4] = {};

  for (int kt = 0; kt < 8; ++kt) {
    int k0 = kt * 32;
    gl16(Ah + (size_t)ar0 * D_DIM + k0 + c_s, &sAh[wid * 1024]);
    gl16(Ah + (size_t)ar1 * D_DIM + k0 + c_s, &sAh[wid * 1024 + 512]);
    gl16(Al + (size_t)ar0 * D_DIM + k0 + c_s, &sAl[wid * 1024]);
    gl16(Al + (size_t)ar1 * D_DIM + k0 + c_s, &sAl[wid * 1024 + 512]);
    gl16(Bh + (size_t)br0 * D_DIM + k0 + c_s, &sBh[wid * 1024]);
    gl16(Bh + (size_t)br1 * D_DIM + k0 + c_s, &sBh[wid * 1024 + 512]);
    gl16(Bl + (size_t)br0 * D_DIM + k0 + c_s, &sBl[wid * 1024]);
    gl16(Bl + (size_t)br1 * D_DIM + k0 + c_s, &sBl[wid * 1024 + 512]);
    __syncthreads();

    bf16x8 ah[4], al[4], bh[4], bl[4];
#pragma unroll
    for (int m = 0; m < 4; ++m) {
      ah[m] = *(const bf16x8*)&sAh[a_off0 + m * 512];
      al[m] = *(const bf16x8*)&sAl[a_off0 + m * 512];
    }
#pragma unroll
    for (int n = 0; n < 4; ++n) {
      bh[n] = *(const bf16x8*)&sBh[b_off0 + n * 512];
      bl[n] = *(const bf16x8*)&sBl[b_off0 + n * 512];
    }
#pragma unroll
    for (int m = 0; m < 4; ++m)
#pragma unroll
      for (int n = 0; n < 4; ++n) {
        acc[m][n] = __builtin_amdgcn_mfma_f32_16x16x32_bf16(ah[m], bh[n], acc[m][n], 0, 0, 0);
        acc[m][n] = __builtin_amdgcn_mfma_f32_16x16x32_bf16(ah[m], bl[n], acc[m][n], 0, 0, 0);
        acc[m][n] = __builtin_amdgcn_mfma_f32_16x16x32_bf16(al[m], bh[n], acc[m][n], 0, 0, 0);
      }
    __syncthreads();
  }

  // C/D layout (m89/m91): col = lane&15, row = (lane>>4)*4 + reg
#pragma unroll
  for (int m = 0; m < 4; ++m) {
    int rr = trow0 + wr * 64 + m * 16 + fq * 4;
#pragma unroll
    for (int n = 0; n < 4; ++n) {
      int cc = col0 + wc * 64 + n * 16 + fr;
#pragma unroll
      for (int r = 0; r < 4; ++r) {
        if (rr + r < rows) dist[(size_t)(rr + r) * Q_N + cc] = acc[m][n][r];
      }
    }
  }
}

// ---- kernel 4: per-row 2048-bin key histogram -> (dmax, b*, count_above) ----
__global__ __launch_bounds__(256) void hist_k(const float* __restrict__ dist,
                                              float4* __restrict__ meta, int row0) {
  int row = blockIdx.x;
  const float4* dp = (const float4*)(dist + (size_t)row * Q_N);
  __shared__ u32 h[4][2048];
  __shared__ u32 s[256];
  __shared__ float wmax[4];
  int tid = threadIdx.x, lane = tid & 63, w = tid >> 6;
  for (int i = tid; i < 8192; i += 256) ((u32*)h)[i] = 0;
  __syncthreads();
  float mx = -1e30f;
  for (int i = 0; i < 64; ++i) {
    float4 v = dp[tid + (i << 8)];
    mx = fmaxf(mx, fmaxf(fmaxf(v.x, v.y), fmaxf(v.z, v.w)));
    atomicAdd(&h[w][fkey(v.x) >> 21], 1u);
    atomicAdd(&h[w][fkey(v.y) >> 21], 1u);
    atomicAdd(&h[w][fkey(v.z) >> 21], 1u);
    atomicAdd(&h[w][fkey(v.w) >> 21], 1u);
  }
  for (int o = 32; o > 0; o >>= 1) mx = fmaxf(mx, __shfl_down(mx, o));
  if (lane == 0) wmax[w] = mx;
  __syncthreads();
  for (int b = tid; b < 2048; b += 256) h[0][b] = h[0][b] + h[1][b] + h[2][b] + h[3][b];
  __syncthreads();
  u32 cs = 0;
  for (int j = 0; j < 8; ++j) cs += h[0][tid * 8 + j];
  s[tid] = cs;
  __syncthreads();
  for (int off = 1; off < 256; off <<= 1) {  // Hillis-Steele suffix scan
    u32 v = (tid + off < 256) ? s[tid + off] : 0u;
    __syncthreads();
    s[tid] += v;
    __syncthreads();
  }
  u32 sfx = s[tid];
  u32 sfx1 = (tid < 255) ? s[tid + 1] : 0u;
  if (sfx >= K_TOP && sfx1 < K_TOP) {  // unique crossing chunk
    u32 cum = sfx1;
    int bstar = tid * 8;
    u32 cab = 0;
    for (int b = tid * 8 + 7; b >= tid * 8; --b) {
      u32 hb = h[0][b];
      if (cum + hb >= K_TOP) { bstar = b; cab = cum; break; }
      cum += hb;
    }
    float dm = fmaxf(fmaxf(wmax[0], wmax[1]), fmaxf(wmax[2], wmax[3]));
    meta[row0 + row] = make_float4(dm, __uint_as_float((u32)bstar), __uint_as_float(cab), 0.0f);
  }
}

// ---- kernel 5: select top-K exactly, softmax-weighted class histogram -------
__global__ __launch_bounds__(256) void select_k(const float* __restrict__ dist,
                                                const int* __restrict__ labels,
                                                const float4* __restrict__ meta,
                                                float* __restrict__ out, int row0) {
  int row = blockIdx.x;
  const float4* dp = (const float4*)(dist + (size_t)row * Q_N);
  float4 mt = meta[row0 + row];
  float dmax = mt.x;
  u32 bstar = __float_as_uint(mt.y);
  int Kp = K_TOP - (int)__float_as_uint(mt.z);
  __shared__ u64 cand[4096];
  __shared__ u32 cnt;
  __shared__ float cls[16];
  __shared__ float den;
  int tid = threadIdx.x;
  if (tid == 0) { cnt = 0; den = 0.0f; }
  if (tid < 16) cls[tid] = 0.0f;
  __syncthreads();
  for (int i = 0; i < 64; ++i) {
    int i4 = tid + (i << 8);
    float4 v = dp[i4];
    float fv[4] = {v.x, v.y, v.z, v.w};
#pragma unroll
    for (int j = 0; j < 4; ++j) {
      u32 u = fkey(fv[j]);
      u32 bin = u >> 21;
      if (bin >= bstar) {
        if (bin > bstar) {  // definitely in top-K
          float wgt = __expf((fv[j] - dmax) * INV_T);
          atomicAdd(&den, wgt);
          atomicAdd(&cls[labels[i4 * 4 + j] & 15], wgt);
        } else {  // boundary-bin candidate
          u32 p = atomicAdd(&cnt, 1u);
          if (p < 4096) cand[p] = ((u64)u << 32) | (u32)(~(u32)(i4 * 4 + j));
        }
      }
    }
  }
  __syncthreads();
  int c = (int)min(cnt, 4096u);
  for (int i = tid; i < c; i += 256) {
    u64 me = cand[i];
    int r = 0;
    for (int j = 0; j < c; ++j) r += (cand[j] > me) ? 1 : 0;
    if (r < Kp) {  // exact rank among candidates; ties broken by smaller index
      u32 u = (u32)(me >> 32);
      u32 idx = ~(u32)(me & 0xffffffffu);
      float f = funkey(u);
      float wgt = __expf((f - dmax) * INV_T);
      atomicAdd(&den, wgt);
      atomicAdd(&cls[labels[idx] & 15], wgt);
    }
  }
  __syncthreads();
  if (tid < N_CLASSES)
    out[(size_t)(row0 + row) * N_CLASSES + tid] = fminf(cls[tid] / den + 1e-5f, 1.0f);
}

// ---- host -------------------------------------------------------------------
extern "C" void kernel_launch(void* const* d_in, const int* in_sizes, int n_in,
                              void* d_out, int out_size, void* d_ws, size_t ws_size,
                              hipStream_t stream) {
  const float* x = (const float*)d_in[0];
  const float* mem = (const float*)d_in[1];
  const int* lbl = (const int*)d_in[2];
  float* out = (float*)d_out;

  char* w = (char*)d_ws;
  u16* mem_hi = (u16*)w;  w += (size_t)Q_N * D_DIM * 2;
  u16* mem_lo = (u16*)w;  w += (size_t)Q_N * D_DIM * 2;
  u16* x_hi = (u16*)w;    w += (size_t)B_ROWS * D_DIM * 2;
  u16* x_lo = (u16*)w;    w += (size_t)B_ROWS * D_DIM * 2;
  float4* meta = (float4*)w;  w += (size_t)B_ROWS * 16;
  float* dist = (float*)w;

  size_t used = (size_t)(w - (char*)d_ws);
  size_t avail = ws_size > used ? ws_size - used : 0;
  int cr = (int)(avail / ((size_t)Q_N * 4));
  if (cr > 256) cr = 256;          // 64MB chunk stays L3-resident
  if (cr >= 64) cr &= ~63;
  if (cr < 1) cr = 1;

  xnorm_k<<<B_ROWS, 256, 0, stream>>>(x, x_hi, x_lo);
  mdecomp_k<<<2048, 256, 0, stream>>>((const float4*)mem, (ushort4*)mem_hi, (ushort4*)mem_lo,
                                      Q_N * D_DIM / 4);

  for (int r0 = 0; r0 < B_ROWS; r0 += cr) {
    int rows = min(cr, B_ROWS - r0);
    dim3 g(Q_N / 128, (rows + 127) / 128);
    gemm3_k<<<g, 256, 0, stream>>>(x_hi, x_lo, mem_hi, mem_lo, dist, r0, rows);
    hist_k<<<rows, 256, 0, stream>>>(dist, meta, r0);
    select_k<<<rows, 256, 0, stream>>>(dist, lbl, meta, out, r0);
  }
}

// Round 2
// 378.094 us; speedup vs baseline: 1.5573x; 1.5573x over previous
//
#include <hip/hip_runtime.h>
#include <hip/hip_bf16.h>

#define B_ROWS 1024
#define D_DIM 256
#define Q_N 65536
#define K_TOP 200
#define N_CLASSES 10
#define INV_T 14.2857142857142857f /* 1/0.07 */

typedef unsigned int u32;
typedef unsigned short u16;
typedef unsigned long long u64;

using bf16x8 = __attribute__((ext_vector_type(8))) __bf16;
using f32x4  = __attribute__((ext_vector_type(4))) float;

// ---- helpers ----------------------------------------------------------------

// order-preserving float->uint key (descending float == descending key)
__device__ __forceinline__ u32 fkey(float f) {
  u32 u = __float_as_uint(f);
  return (u >> 31) ? ~u : (u | 0x80000000u);
}
__device__ __forceinline__ float funkey(u32 u) {
  return __uint_as_float((u >> 31) ? (u & 0x7fffffffu) : ~u);
}
__device__ __forceinline__ u16 bf16_rn(float f) {
  u32 u = __float_as_uint(f);
  u32 r = (u + 0x7fffu + ((u >> 16) & 1u)) >> 16;
  return (u16)r;
}
// f ~= hi + lo with hi,lo bf16 (error ~2^-16 relative)
__device__ __forceinline__ void split2(float f, u16& h, u16& l) {
  u16 hh = bf16_rn(f);
  float hf = __uint_as_float(((u32)hh) << 16);
  h = hh;
  l = bf16_rn(f - hf);
}

__device__ __forceinline__ void gl16(const void* g, void* l) {
  __builtin_amdgcn_global_load_lds((const __attribute__((address_space(1))) u32*)g,
                                   (__attribute__((address_space(3))) u32*)l, 16, 0, 0);
}

// ---- kernel 1: x row-normalize + bf16 hi/lo split ---------------------------
__global__ __launch_bounds__(256) void xnorm_k(const float* __restrict__ x,
                                               u16* __restrict__ xh, u16* __restrict__ xl) {
  int row = blockIdx.x, t = threadIdx.x;
  int lane = t & 63, w = t >> 6;
  float v = x[row * D_DIM + t];
  float s = v * v;
  for (int o = 32; o > 0; o >>= 1) s += __shfl_down(s, o);
  __shared__ float ws[4];
  if (lane == 0) ws[w] = s;
  __syncthreads();
  if (t == 0) ws[0] = ws[0] + ws[1] + ws[2] + ws[3];
  __syncthreads();
  float inv = 1.0f / fmaxf(sqrtf(ws[0]), 1e-12f);
  u16 h, l;
  split2(v * inv, h, l);
  xh[row * D_DIM + t] = h;
  xl[row * D_DIM + t] = l;
}

// ---- kernel 2: memory bf16 hi/lo split --------------------------------------
__global__ __launch_bounds__(256) void mdecomp_k(const float4* __restrict__ m,
                                                 ushort4* __restrict__ mh,
                                                 ushort4* __restrict__ ml, int n4) {
  int i = blockIdx.x * blockDim.x + threadIdx.x;
  int stride = gridDim.x * blockDim.x;
  for (; i < n4; i += stride) {
    float4 v = m[i];
    ushort4 h, l;
    split2(v.x, h.x, l.x);
    split2(v.y, h.y, l.y);
    split2(v.z, h.z, l.z);
    split2(v.w, h.w, l.w);
    mh[i] = h;
    ml[i] = l;
  }
}

// ---- kernel 3: dist = A*B^T via bf16x3 MFMA (128x128 tile, BK=32) -----------
// A: [1024][256] (x hi/lo), B: [65536][256] (memory hi/lo), both K-contiguous.
// grid.x = row tiles (few), grid.y = col tiles (512): consecutive blocks share
// the same B col-tile -> B re-read served from L2 instead of 4x L3/HBM fetch.
__global__ __launch_bounds__(256) void gemm3_k(const u16* __restrict__ Ah, const u16* __restrict__ Al,
                                               const u16* __restrict__ Bh, const u16* __restrict__ Bl,
                                               float* __restrict__ dist, int row0, int rows) {
  __shared__ u16 sAh[4096], sAl[4096], sBh[4096], sBl[4096];  // 4 x 8KB
  int tid = threadIdx.x;
  int lane = tid & 63, wid = tid >> 6;
  int wr = wid >> 1, wc = wid & 1;
  int col0 = blockIdx.y << 7;
  int trow0 = blockIdx.x << 7;

  // staging: linear LDS, wave-uniform base + lane*16B (global_load_lds contract)
  int e0 = wid * 1024 + lane * 8;  // element offset of j=0 16B block
  int r_s = e0 >> 5, c_s = e0 & 31;
  int ar0 = row0 + trow0 + r_s;
  int ar1 = ar0 + 16;
  ar0 = min(ar0, B_ROWS - 1);  // tail tiles: clamp (store-guarded anyway)
  ar1 = min(ar1, B_ROWS - 1);
  int br0 = col0 + r_s, br1 = br0 + 16;

  // fragment addressing: A lane: row=lane&15, k=(lane>>4)*8+j  (K-contiguous LDS)
  int fr = lane & 15, fq = lane >> 4;
  int a_off0 = (wr * 64 + fr) * 32 + fq * 8;
  int b_off0 = (wc * 64 + fr) * 32 + fq * 8;

  f32x4 acc[4][4] = {};

  for (int kt = 0; kt < 8; ++kt) {
    int k0 = kt * 32;
    gl16(Ah + (size_t)ar0 * D_DIM + k0 + c_s, &sAh[wid * 1024]);
    gl16(Ah + (size_t)ar1 * D_DIM + k0 + c_s, &sAh[wid * 1024 + 512]);
    gl16(Al + (size_t)ar0 * D_DIM + k0 + c_s, &sAl[wid * 1024]);
    gl16(Al + (size_t)ar1 * D_DIM + k0 + c_s, &sAl[wid * 1024 + 512]);
    gl16(Bh + (size_t)br0 * D_DIM + k0 + c_s, &sBh[wid * 1024]);
    gl16(Bh + (size_t)br1 * D_DIM + k0 + c_s, &sBh[wid * 1024 + 512]);
    gl16(Bl + (size_t)br0 * D_DIM + k0 + c_s, &sBl[wid * 1024]);
    gl16(Bl + (size_t)br1 * D_DIM + k0 + c_s, &sBl[wid * 1024 + 512]);
    __syncthreads();

    bf16x8 ah[4], al[4], bh[4], bl[4];
#pragma unroll
    for (int m = 0; m < 4; ++m) {
      ah[m] = *(const bf16x8*)&sAh[a_off0 + m * 512];
      al[m] = *(const bf16x8*)&sAl[a_off0 + m * 512];
    }
#pragma unroll
    for (int n = 0; n < 4; ++n) {
      bh[n] = *(const bf16x8*)&sBh[b_off0 + n * 512];
      bl[n] = *(const bf16x8*)&sBl[b_off0 + n * 512];
    }
#pragma unroll
    for (int m = 0; m < 4; ++m)
#pragma unroll
      for (int n = 0; n < 4; ++n) {
        acc[m][n] = __builtin_amdgcn_mfma_f32_16x16x32_bf16(ah[m], bh[n], acc[m][n], 0, 0, 0);
        acc[m][n] = __builtin_amdgcn_mfma_f32_16x16x32_bf16(ah[m], bl[n], acc[m][n], 0, 0, 0);
        acc[m][n] = __builtin_amdgcn_mfma_f32_16x16x32_bf16(al[m], bh[n], acc[m][n], 0, 0, 0);
      }
    __syncthreads();
  }

  // C/D layout (m89/m91): col = lane&15, row = (lane>>4)*4 + reg
#pragma unroll
  for (int m = 0; m < 4; ++m) {
    int rr = trow0 + wr * 64 + m * 16 + fq * 4;
#pragma unroll
    for (int n = 0; n < 4; ++n) {
      int cc = col0 + wc * 64 + n * 16 + fr;
#pragma unroll
      for (int r = 0; r < 4; ++r) {
        if (rr + r < rows) dist[(size_t)(rr + r) * Q_N + cc] = acc[m][n][r];
      }
    }
  }
}

// ---- kernel 4: fused top-K + softmax class scores, one pass over dist -------
// One block (1024 thr) per row. Sample 4096 elems -> coarse key threshold
// guaranteeing >=200 survivors (w/ deterministic retry), collect ~1K candidate
// (key,idx) pairs in LDS during the single full read, then fine-histogram +
// exact boundary ranking entirely in LDS.
__global__ __launch_bounds__(1024) void topk_k(const float* __restrict__ dist,
                                               const int* __restrict__ labels,
                                               float* __restrict__ out, int row0) {
  constexpr int CAP = 6144;
  constexpr u32 ST = 64;  // sample count target (sample=1/16 -> E[true]=1024)
  __shared__ u32 cand_key[CAP];   // 24 KB
  __shared__ u32 cand_idx[CAP];   // 24 KB
  __shared__ u32 fhist[2048];     // 8 KB
  __shared__ u32 shist[1024];     // 4 KB (sample hist, reused as scan scratch)
  __shared__ u32 bidx[2048];      // 8 KB
  __shared__ float cls[16];
  __shared__ float den_s;
  __shared__ u32 cnt_s, bcnt_s, thr_s, maxk_s, bstar_s, cab_s;

  const int tid = threadIdx.x;
  const int row = blockIdx.x;
  const float4* dp = (const float4*)(dist + (size_t)row * Q_N);

  // ---- phase 0: sample -> coarse threshold key ----
  shist[tid] = 0;
  if (tid < 16) cls[tid] = 0.f;
  if (tid == 0) { den_s = 0.f; bcnt_s = 0; maxk_s = 0; bstar_s = 0; cab_s = 0; }
  __syncthreads();
  float4 sv = dp[tid << 4];
  atomicAdd(&shist[fkey(sv.x) >> 22], 1u);
  atomicAdd(&shist[fkey(sv.y) >> 22], 1u);
  atomicAdd(&shist[fkey(sv.z) >> 22], 1u);
  atomicAdd(&shist[fkey(sv.w) >> 22], 1u);
  __syncthreads();
  for (int off = 1; off < 1024; off <<= 1) {  // suffix scan
    u32 v = (tid + off < 1024) ? shist[tid + off] : 0u;
    __syncthreads();
    shist[tid] += v;
    __syncthreads();
  }
  if (shist[tid] >= ST && (tid == 1023 || shist[tid + 1] < ST)) thr_s = (u32)tid;
  __syncthreads();
  u32 tkey = thr_s << 22;

  // ---- phase 1: single full read, collect candidates >= tkey ----
  int attempt = 0;
  u32 c;
  while (true) {
    if (tid == 0) cnt_s = 0;
    __syncthreads();
#pragma unroll
    for (int b = 0; b < 4; ++b) {
      float4 v0 = dp[tid + ((b * 4 + 0) << 10)];
      float4 v1 = dp[tid + ((b * 4 + 1) << 10)];
      float4 v2 = dp[tid + ((b * 4 + 2) << 10)];
      float4 v3 = dp[tid + ((b * 4 + 3) << 10)];
      float4 vv[4] = {v0, v1, v2, v3};
#pragma unroll
      for (int u = 0; u < 4; ++u) {
        int gi0 = (tid + ((b * 4 + u) << 10)) << 2;
        float fv[4] = {vv[u].x, vv[u].y, vv[u].z, vv[u].w};
#pragma unroll
        for (int j = 0; j < 4; ++j) {
          u32 k = fkey(fv[j]);
          if (k >= tkey) {
            u32 p = atomicAdd(&cnt_s, 1u);
            if (p < CAP) { cand_key[p] = k; cand_idx[p] = (u32)(gi0 + j); }
          }
        }
      }
    }
    __syncthreads();
    c = cnt_s;
    if ((c >= K_TOP && c <= CAP) || ++attempt >= 6) break;
    if (tid == 0) thr_s += (c > CAP) ? 1u : (u32)-1;
    __syncthreads();
    tkey = thr_s << 22;
  }
  if (c > CAP) c = CAP;

  // ---- phase 2: fine histogram over candidates, find boundary bin ----
  fhist[tid] = 0;
  fhist[tid + 1024] = 0;
  __syncthreads();
  for (u32 i = tid; i < c; i += 1024) {
    u32 k = cand_key[i];
    atomicMax(&maxk_s, k);
    u32 fb = (k - tkey) >> 14;
    if (fb > 2047u) fb = 2047u;
    atomicAdd(&fhist[fb], 1u);
  }
  __syncthreads();
  shist[tid] = fhist[2 * tid] + fhist[2 * tid + 1];
  __syncthreads();
  for (int off = 1; off < 1024; off <<= 1) {  // suffix scan (2-bin chunks)
    u32 v = (tid + off < 1024) ? shist[tid + off] : 0u;
    __syncthreads();
    shist[tid] += v;
    __syncthreads();
  }
  {
    u32 sfx = shist[tid];
    u32 sfx1 = (tid < 1023) ? shist[tid + 1] : 0u;
    if (sfx >= K_TOP && sfx1 < K_TOP) {
      u32 cum = sfx1;
      int bs = 2 * tid;
      u32 cab = 0;
      for (int b = 2 * tid + 1; b >= 2 * tid; --b) {
        u32 hb = fhist[b];
        if (cum + hb >= K_TOP) { bs = b; cab = cum; break; }
        cum += hb;
      }
      bstar_s = (u32)bs;
      cab_s = cab;
    }
  }
  __syncthreads();

  // ---- phase 3: accumulate definite items, rank boundary bin exactly ----
  float dmax = funkey(maxk_s);
  u32 bstar = bstar_s;
  int Kp = K_TOP - (int)cab_s;
  for (u32 i = tid; i < c; i += 1024) {
    u32 k = cand_key[i];
    u32 fb = (k - tkey) >> 14;
    if (fb > 2047u) fb = 2047u;
    if (fb > bstar) {  // definitely in top-K
      float wgt = __expf((funkey(k) - dmax) * INV_T);
      atomicAdd(&den_s, wgt);
      atomicAdd(&cls[labels[cand_idx[i]] & 15], wgt);
    } else if (fb == bstar) {
      u32 p = atomicAdd(&bcnt_s, 1u);
      if (p < 2048u) bidx[p] = i;
    }
  }
  __syncthreads();
  int bc = (int)min(bcnt_s, 2048u);
  for (int i = tid; i < bc; i += 1024) {
    u32 ci = bidx[i];
    u32 k = cand_key[ci];
    u32 gi = cand_idx[ci];
    int r = 0;
    for (int j = 0; j < bc; ++j) {
      u32 cj = bidx[j];
      u32 kj = cand_key[cj];
      r += (kj > k || (kj == k && cand_idx[cj] < gi)) ? 1 : 0;
    }
    if (r < Kp) {  // exact rank; ties broken by smaller index (lax.top_k order)
      float wgt = __expf((funkey(k) - dmax) * INV_T);
      atomicAdd(&den_s, wgt);
      atomicAdd(&cls[labels[gi] & 15], wgt);
    }
  }
  __syncthreads();
  if (tid < N_CLASSES)
    out[(size_t)(row0 + row) * N_CLASSES + tid] = fminf(cls[tid] / den_s + 1e-5f, 1.0f);
}

// ---- host -------------------------------------------------------------------
extern "C" void kernel_launch(void* const* d_in, const int* in_sizes, int n_in,
                              void* d_out, int out_size, void* d_ws, size_t ws_size,
                              hipStream_t stream) {
  const float* x = (const float*)d_in[0];
  const float* mem = (const float*)d_in[1];
  const int* lbl = (const int*)d_in[2];
  float* out = (float*)d_out;

  char* w = (char*)d_ws;
  u16* mem_hi = (u16*)w;  w += (size_t)Q_N * D_DIM * 2;
  u16* mem_lo = (u16*)w;  w += (size_t)Q_N * D_DIM * 2;
  u16* x_hi = (u16*)w;    w += (size_t)B_ROWS * D_DIM * 2;
  u16* x_lo = (u16*)w;    w += (size_t)B_ROWS * D_DIM * 2;
  float* dist = (float*)w;

  size_t used = (size_t)(w - (char*)d_ws);
  size_t avail = ws_size > used ? ws_size - used : 0;
  int cr = (int)(avail / ((size_t)Q_N * 4));
  if (cr > 512) cr = 512;          // 128MB chunk still L3-resident w/ operands
  if (cr >= 64) cr &= ~63;
  if (cr < 1) cr = 1;

  xnorm_k<<<B_ROWS, 256, 0, stream>>>(x, x_hi, x_lo);
  mdecomp_k<<<2048, 256, 0, stream>>>((const float4*)mem, (ushort4*)mem_hi, (ushort4*)mem_lo,
                                      Q_N * D_DIM / 4);

  for (int r0 = 0; r0 < B_ROWS; r0 += cr) {
    int rows = min(cr, B_ROWS - r0);
    dim3 g((rows + 127) / 128, Q_N / 128);
    gemm3_k<<<g, 256, 0, stream>>>(x_hi, x_lo, mem_hi, mem_lo, dist, r0, rows);
    topk_k<<<rows, 1024, 0, stream>>>(dist, lbl, out, r0);
  }
}